// Round 6
// baseline (452.654 us; speedup 1.0000x reference)
//
#include <hip/hip_runtime.h>
#include <hip/hip_bf16.h>
#include <math.h>

// ScaledDotProductAttention, masked_softmax semantics (clip ±15, mask-mult,
// exp(x - max), re-mask, /(sum+1e-6)). B=16, L=2048, D=64, TEMP=8.
//
// Round-6: barrier-free wave-independent structure.
//   Evidence: R5 out_kernel at 39% occupancy still idle on all pipes while
//   fillBuffer hits 6.8 TB/s at 10% -> barrier-locked waves + long serial
//   critical path were the problem, not occupancy alone. FETCH=19MB -> K/V/Q
//   are L2-resident -> K LDS staging was pure overhead.
//   kernel 1 (sums): block = 16 q x 2048 k; each wave a private 512-k range,
//     K fragments direct-from-global, no LDS staging, no main-loop barriers.
//     Writes final sums[b][q] (one end-combine) + packed mask bitmask to ws.
//   kernel 2 (out):  block = 16 q x 2048 k; wave = private 512-k quarter.
//     S recomputed (K direct), attn written normalized, PV accumulated with
//     per-wave V^T LDS tile (intra-wave only). One barrier: O-combine in LDS.

typedef __bf16 bf16x8v __attribute__((ext_vector_type(8)));
typedef __bf16 bf16x4v __attribute__((ext_vector_type(4)));
typedef __bf16 bf16x2v __attribute__((ext_vector_type(2)));
typedef float  f32x4   __attribute__((ext_vector_type(4)));
typedef int    i32x4   __attribute__((ext_vector_type(4)));

#define B_  16
#define L_  2048
#define D_  64

// swizzle for per-wave [64 d][32 k] bf16 V^T tile (64B rows):
// slot = ((row>>1)&3) ^ (row>>4)  -> conflict-free reads AND writes
__device__ __forceinline__ int swzV(int row, int colb) {
    return row * 64 + (colb ^ ((((row >> 1) & 3) ^ ((row >> 4) & 3)) << 4));
}
// swizzle for per-wave [16 q][32 k] bf16 P tile (64B rows)
__device__ __forceinline__ int swzP(int row, int colb) {
    return row * 64 + (colb ^ (((row >> 1) & 3) << 4));
}

// K fragment (MFMA A operand) direct from global: row = one K row (fp32),
// lane grabs d = g*8..g*8+7 and d = 32+g*8..+7, scaled and bf16-converted.
__device__ __forceinline__ void kfrag(const float* __restrict__ krow, int g,
                                      bf16x8v& a0, bf16x8v& a1) {
    const f32x4* p0 = (const f32x4*)(krow + g * 8);
    const f32x4* p1 = (const f32x4*)(krow + 32 + g * 8);
    f32x4 x0 = p0[0], x1 = p0[1], x2 = p1[0], x3 = p1[1];
    #pragma unroll
    for (int j = 0; j < 4; ++j) {
        a0[j] = (__bf16)x0[j]; a0[4 + j] = (__bf16)x1[j];
        a1[j] = (__bf16)x2[j]; a1[4 + j] = (__bf16)x3[j];
    }
}

// ============================ KERNEL 1: sums ============================
// 2048 blocks x 256. Block: batch b, 16 q-rows. Wave w: k in [w*512,(w+1)*512).
template<bool WB>
__global__ __launch_bounds__(256, 6)
void sdpa_sum_kernel(const float* __restrict__ qg,
                     const float* __restrict__ kg,
                     const int*   __restrict__ mg,
                     float* __restrict__ sums,          // [B][L]
                     unsigned short* __restrict__ bitm) // [b][q][kc32][g] u16
{
    __shared__ float sbuf[4][16];

    const int t  = threadIdx.x;
    const int w  = t >> 6;
    const int l  = t & 63;
    const int lq = l & 15;
    const int g  = l >> 4;

    const int bid  = blockIdx.x;
    const int virt = (bid & 7) * 256 + (bid >> 3);   // XCD remap
    const int b    = virt >> 7;
    const int q0   = (virt & 127) * 16;
    const int qi   = q0 + lq;

    const size_t kvbase = (size_t)b * (L_ * D_);
    const size_t mrow   = ((size_t)b * L_ + qi) * L_;

    // Q fragment (B operand), 1/8 folded
    bf16x8v qf0, qf1;
    {
        const float* qrow = qg + ((size_t)b * L_ + qi) * D_;
        const f32x4* p0 = (const f32x4*)(qrow + g * 8);
        const f32x4* p1 = (const f32x4*)(qrow + 32 + g * 8);
        f32x4 x0 = p0[0], x1 = p0[1], x2 = p1[0], x3 = p1[1];
        #pragma unroll
        for (int j = 0; j < 4; ++j) {
            qf0[j]     = (__bf16)(x0[j] * 0.125f);
            qf0[4 + j] = (__bf16)(x1[j] * 0.125f);
            qf1[j]     = (__bf16)(x2[j] * 0.125f);
            qf1[4 + j] = (__bf16)(x3[j] * 0.125f);
        }
    }

    const int kq = w * 512;
    float rS = 0.f;
    #pragma unroll 1
    for (int kci = 0; kci < 8; ++kci) {       // 8 x 64-k tiles
        unsigned mbits = 0;
        #pragma unroll
        for (int sub = 0; sub < 4; ++sub) {
            const int kr = kq + kci * 64 + sub * 16 + lq;
            bf16x8v a0, a1;
            kfrag(kg + kvbase + (size_t)kr * D_, g, a0, a1);
            f32x4 s = {0.f, 0.f, 0.f, 0.f};
            s = __builtin_amdgcn_mfma_f32_16x16x32_bf16(a0, qf0, s, 0, 0, 0);
            s = __builtin_amdgcn_mfma_f32_16x16x32_bf16(a1, qf1, s, 0, 0, 0);
            i32x4 mv = *(const i32x4*)(mg + mrow + kq + kci * 64 + sub * 16 + g * 4);
            #pragma unroll
            for (int r = 0; r < 4; ++r) {
                bool mm = (mv[r] != 0);
                mbits |= mm ? (1u << (sub * 4 + r)) : 0u;
                float y = mm ? (fminf(fmaxf(s[r], -15.f), 15.f) - 15.f) : -1e30f;
                rS += __expf(y);
            }
        }
        if (WB) bitm[(size_t)(b * L_ + qi) * 128 + (w * 8 + kci) * 4 + g] =
                    (unsigned short)mbits;
    }
    rS += __shfl_xor(rS, 16, 64);
    rS += __shfl_xor(rS, 32, 64);
    if (l < 16) sbuf[w][l] = rS;
    __syncthreads();
    if (w == 0 && l < 16)
        sums[(size_t)b * L_ + q0 + l] = sbuf[0][l] + sbuf[1][l] + sbuf[2][l] + sbuf[3][l];
}

// ============================ KERNEL 2: output ============================
// 2048 blocks x 256. Block: batch b, 16 q-rows. Wave w: k-quarter w.
// Barrier-free main loop; one final barrier for the 4-way O combine.
template<bool UB>
__global__ __launch_bounds__(256, 4)
void sdpa_out_kernel(const float* __restrict__ qg,
                     const float* __restrict__ kg,
                     const float* __restrict__ vg,
                     const int*   __restrict__ mg,
                     const float* __restrict__ sums,
                     const unsigned short* __restrict__ bitm,
                     float* __restrict__ outg,    // [B][L][D]
                     float* __restrict__ attng)   // [B][L][L]
{
    __shared__ __align__(16) char VtB[4][4096];    // per-wave V^T [64d][32k] bf16 swz
    __shared__ __align__(16) char PwB[4][1024];    // per-wave P   [16q][32k] bf16 swz
    __shared__ __align__(16) float Obuf[4][16][68];// partial O combine

    const int t  = threadIdx.x;
    const int w  = t >> 6;
    const int l  = t & 63;
    const int lq = l & 15;
    const int g  = l >> 4;

    const int bid  = blockIdx.x;
    const int virt = (bid & 7) * 256 + (bid >> 3);   // XCD remap
    const int b    = virt >> 7;
    const int q0   = (virt & 127) * 16;
    const int qi   = q0 + lq;

    const size_t kvbase = (size_t)b * (L_ * D_);
    const size_t mrow   = ((size_t)b * L_ + qi) * L_;

    const float inv = 1.f / (sums[(size_t)b * L_ + qi] + 1e-6f);

    // Q fragment
    bf16x8v qf0, qf1;
    {
        const float* qrow = qg + ((size_t)b * L_ + qi) * D_;
        const f32x4* p0 = (const f32x4*)(qrow + g * 8);
        const f32x4* p1 = (const f32x4*)(qrow + 32 + g * 8);
        f32x4 x0 = p0[0], x1 = p0[1], x2 = p1[0], x3 = p1[1];
        #pragma unroll
        for (int j = 0; j < 4; ++j) {
            qf0[j]     = (__bf16)(x0[j] * 0.125f);
            qf0[4 + j] = (__bf16)(x1[j] * 0.125f);
            qf1[j]     = (__bf16)(x2[j] * 0.125f);
            qf1[4 + j] = (__bf16)(x3[j] * 0.125f);
        }
    }

    char* Vt = VtB[w];
    char* Pw = PwB[w];
    const int kp = l & 15;      // k-pair for V staging
    const int dq = l >> 4;      // d-quarter for V staging

    f32x4 acc[4];
    #pragma unroll
    for (int i = 0; i < 4; ++i) acc[i] = (f32x4){0.f, 0.f, 0.f, 0.f};

    const int kq = w * 512;
    #pragma unroll 1
    for (int ch = 0; ch < 16; ++ch) {         // 16 x 32-k chunks
        const int k0 = kq + ch * 32;

        // ---- stage V chunk -> per-wave V^T tile (intra-wave, no barrier) ----
        {
            const float* vr0 = vg + kvbase + (size_t)(k0 + 2 * kp) * D_ + dq * 16;
            const f32x4* pA = (const f32x4*)vr0;
            const f32x4* pB = (const f32x4*)(vr0 + D_);
            f32x4 rA0 = pA[0], rA1 = pA[1], rA2 = pA[2], rA3 = pA[3];
            f32x4 rB0 = pB[0], rB1 = pB[1], rB2 = pB[2], rB3 = pB[3];
            #pragma unroll
            for (int jj = 0; jj < 4; ++jj) {
                f32x4 xa = (jj == 0) ? rA0 : (jj == 1) ? rA1 : (jj == 2) ? rA2 : rA3;
                f32x4 xb = (jj == 0) ? rB0 : (jj == 1) ? rB1 : (jj == 2) ? rB2 : rB3;
                #pragma unroll
                for (int c = 0; c < 4; ++c) {
                    const int d = dq * 16 + jj * 4 + c;
                    bf16x2v pr; pr[0] = (__bf16)xa[c]; pr[1] = (__bf16)xb[c];
                    *(bf16x2v*)(Vt + swzV(d, kp * 4)) = pr;
                }
            }
        }

        // ---- QK for the 2 subtiles, attn write, P stash ----
        unsigned mb16 = 0;
        if (UB) mb16 = bitm[(size_t)(b * L_ + qi) * 128 + (k0 >> 6) * 4 + g];
        #pragma unroll
        for (int st = 0; st < 2; ++st) {
            const int kr = k0 + st * 16 + lq;
            bf16x8v a0, a1;
            kfrag(kg + kvbase + (size_t)kr * D_, g, a0, a1);
            f32x4 s = {0.f, 0.f, 0.f, 0.f};
            s = __builtin_amdgcn_mfma_f32_16x16x32_bf16(a0, qf0, s, 0, 0, 0);
            s = __builtin_amdgcn_mfma_f32_16x16x32_bf16(a1, qf1, s, 0, 0, 0);

            const int subg = ((k0 >> 4) & 3) + st;
            i32x4 mv;
            if (!UB) mv = *(const i32x4*)(mg + mrow + k0 + st * 16 + g * 4);
            f32x4 pv; bf16x4v pb;
            #pragma unroll
            for (int r = 0; r < 4; ++r) {
                bool mm = UB ? (((mb16 >> (subg * 4 + r)) & 1u) != 0u) : (mv[r] != 0);
                float y = mm ? (fminf(fmaxf(s[r], -15.f), 15.f) - 15.f) : -1e30f;
                float p = __expf(y) * inv;
                pv[r] = p; pb[r] = (__bf16)p;
            }
            *(f32x4*)(attng + mrow + k0 + st * 16 + g * 4) = pv;
            *(bf16x4v*)(Pw + swzP(lq, (st * 16 + g * 4) * 2)) = pb;
        }

        // ---- PV: one 32-deep MFMA per d-tile (same-wave LDS RAW) ----
        bf16x8v pa = *(const bf16x8v*)(Pw + swzP(lq, g * 16));
        #pragma unroll
        for (int dt = 0; dt < 4; ++dt) {
            bf16x8v vb = *(const bf16x8v*)(Vt + swzV(dt * 16 + lq, g * 16));
            acc[dt] = __builtin_amdgcn_mfma_f32_16x16x32_bf16(pa, vb, acc[dt], 0, 0, 0);
        }
    }

    // ---- combine partial O across the 4 k-quarters ----
    #pragma unroll
    for (int dt = 0; dt < 4; ++dt)
        #pragma unroll
        for (int r = 0; r < 4; ++r)
            Obuf[w][g * 4 + r][dt * 16 + lq] = acc[dt][r];
    __syncthreads();
    {
        const int r  = w * 4 + (l >> 4);     // q-local row this lane outputs
        const int d0 = (l & 15) * 4;
        f32x4 o = *(const f32x4*)&Obuf[0][r][d0];
        #pragma unroll
        for (int wv = 1; wv < 4; ++wv) {
            f32x4 ov = *(const f32x4*)&Obuf[wv][r][d0];
            o[0] += ov[0]; o[1] += ov[1]; o[2] += ov[2]; o[3] += ov[3];
        }
        *(f32x4*)(outg + ((size_t)b * L_ + q0 + r) * D_ + d0) = o;
    }
}

extern "C" void kernel_launch(void* const* d_in, const int* in_sizes, int n_in,
                              void* d_out, int out_size, void* d_ws, size_t ws_size,
                              hipStream_t stream) {
    (void)in_sizes; (void)n_in; (void)out_size;
    const float* q = (const float*)d_in[0];
    const float* k = (const float*)d_in[1];
    const float* v = (const float*)d_in[2];
    const int*   m = (const int*)d_in[3];
    float* out  = (float*)d_out;
    float* attn = out + (size_t)B_ * L_ * D_;

    float* sums = (float*)d_ws;                                    // 128 KB
    unsigned short* bitm = (unsigned short*)((char*)d_ws + 131072); // 8 MB
    const size_t need = 131072 + (size_t)B_ * L_ * 128 * 2;

    dim3 blk(256), grd(2048);
    if (ws_size >= need) {
        hipLaunchKernelGGL((sdpa_sum_kernel<true>),  grd, blk, 0, stream,
                           q, k, m, sums, bitm);
        hipLaunchKernelGGL((sdpa_out_kernel<true>),  grd, blk, 0, stream,
                           q, k, v, m, sums, bitm, out, attn);
    } else {
        hipLaunchKernelGGL((sdpa_sum_kernel<false>), grd, blk, 0, stream,
                           q, k, m, sums, nullptr);
        hipLaunchKernelGGL((sdpa_out_kernel<false>), grd, blk, 0, stream,
                           q, k, v, m, sums, nullptr, out, attn);
    }
}

// Round 7
// 176.145 us; speedup vs baseline: 2.5698x; 2.5698x over previous
//
#include <hip/hip_runtime.h>
#include <hip/hip_bf16.h>
#include <math.h>

// ScaledDotProductAttention, masked_softmax semantics (clip ±15, mask-mult,
// exp(x - max), re-mask, /(sum+1e-6)). B=16, L=2048, D=64, TEMP=8.
//
// Round-7 = R4 pipeline (best-known ~185us: dbuf LDS, depth-1 reg prefetch,
// lgkm-only barriers, fixed shift M'=15, XCD remap) + access-granularity fixes:
//  - attn store: P staged f32 in per-wave swizzled LDS, stored as 4x(4 rows x
//    256B contiguous) instead of 16-row x 64B scatter.
//  - mask load: row-contiguous per lane (4 rows x 256B per instr), bits
//    redistributed intra-wave via a 1KB LDS nibble table.

typedef __bf16 bf16x8v __attribute__((ext_vector_type(8)));
typedef __bf16 bf16x4v __attribute__((ext_vector_type(4)));
typedef __bf16 bf16x2v __attribute__((ext_vector_type(2)));
typedef float  f32x4   __attribute__((ext_vector_type(4)));
typedef int    i32x4   __attribute__((ext_vector_type(4)));

#define B_  16
#define L_  2048
#define D_  64
#define NKC 32

// swizzled byte offset within a [rows][64] bf16 tile (128 B per row)
__device__ __forceinline__ int swz(int row, int colb) {
    return (row * 128 + colb) ^ ((row & 7) << 4);
}
// swizzled byte offset within a [16 rows][64 f32] tile (256 B per row)
__device__ __forceinline__ int swzF(int row, int colb) {
    return row * 256 + (colb ^ ((row & 7) << 4));
}

// barrier WITHOUT the vmcnt(0) drain: ds_writes visible (lgkmcnt), global
// prefetch loads stay in flight.
__device__ __forceinline__ void bar() {
    asm volatile("s_waitcnt lgkmcnt(0)" ::: "memory");
    __builtin_amdgcn_s_barrier();
}

__global__ __launch_bounds__(256, 2)
void sdpa_kernel(const float* __restrict__ qg,
                 const float* __restrict__ kg,
                 const float* __restrict__ vg,
                 const int*   __restrict__ mg,
                 float* __restrict__ outg,    // [B][L][D]
                 float* __restrict__ attng)   // [B][L][L]
{
    __shared__ __align__(16) char KtB[2][8192];   // K tile bf16 [64][64] swz
    __shared__ __align__(16) char VtB[2][8192];   // V^T tile bf16 [d][k] swz
    __shared__ __align__(16) char PwB[4][2048];   // per-wave P bf16 [16][64] swz
    __shared__ __align__(16) char PfB[4][4096];   // per-wave P f32 [16][64] swzF
    __shared__ unsigned short Ml[NKC][256];       // mask bits [kc][thread]
    __shared__ unsigned Mn32[4][64];              // per-wave nibble xchg

    const int t  = threadIdx.x;
    const int w  = t >> 6;
    const int l  = t & 63;
    const int lq = l & 15;        // q within wave tile (MFMA col / A row)
    const int g  = l >> 4;        // 4-lane group

    // XCD-grouping remap: 512 blocks = 8 XCDs x 64
    const int bid  = blockIdx.x;
    const int virt = (bid & 7) * 64 + (bid >> 3);
    const int b  = virt >> 5;
    const int q0 = (virt & 31) * 64;
    const int qi = q0 + w * 16 + lq;

    const size_t kvbase = (size_t)b * (L_ * D_);
    const size_t mrow   = ((size_t)b * L_ + qi) * L_;   // this lane's attn/mask row
    const size_t qwrow  = (size_t)b * L_ + q0 + w * 16; // wave's first q row

    // ---- Q fragments (B operand), 1/8 temperature folded in ----
    bf16x8v qf0, qf1;
    {
        const float* qrow = qg + ((size_t)b * L_ + qi) * D_;
        const f32x4* p0 = (const f32x4*)(qrow + g * 8);
        const f32x4* p1 = (const f32x4*)(qrow + 32 + g * 8);
        f32x4 x0 = p0[0], x1 = p0[1], x2 = p1[0], x3 = p1[1];
        #pragma unroll
        for (int j = 0; j < 4; ++j) {
            qf0[j]     = (__bf16)(x0[j] * 0.125f);
            qf0[4 + j] = (__bf16)(x1[j] * 0.125f);
            qf1[j]     = (__bf16)(x2[j] * 0.125f);
            qf1[4 + j] = (__bf16)(x3[j] * 0.125f);
        }
    }

    // ---- staging geometry ----
    const int sr  = t >> 2;               // K-tile row this thread stages
    const int scb = (t & 3) * 32;         // byte col (16 bf16 = 32 B)
    const float* kbase  = kg + kvbase + (size_t)sr * D_ + (t & 3) * 16;
    const float* vbase0 = vg + kvbase + (size_t)(2 * (t & 31)) * D_ + (t >> 5) * 8;
    const int dg = t >> 5, kp = t & 31;
    // coalesced mask base: lane row = l>>4 (+4j), cols (l&15)*4
    const int* mbase = mg + (qwrow + (l >> 4)) * L_ + (l & 15) * 4;

    auto loadK = [&](int kc, f32x4& a, f32x4& bb, f32x4& c, f32x4& d) {
        const f32x4* s = (const f32x4*)(kbase + (size_t)kc * (64 * D_));
        a = s[0]; bb = s[1]; c = s[2]; d = s[3];
    };
    auto writeK = [&](char* buf, f32x4 a, f32x4 bb, f32x4 c, f32x4 d) {
        bf16x8v h0, h1;
        #pragma unroll
        for (int j = 0; j < 4; ++j) {
            h0[j] = (__bf16)a[j]; h0[4 + j] = (__bf16)bb[j];
            h1[j] = (__bf16)c[j]; h1[4 + j] = (__bf16)d[j];
        }
        *(bf16x8v*)(buf + swz(sr, scb))      = h0;
        *(bf16x8v*)(buf + swz(sr, scb + 16)) = h1;
    };
    auto loadV = [&](int kc, f32x4& a, f32x4& bb, f32x4& c, f32x4& d) {
        const float* r0 = vbase0 + (size_t)kc * (64 * D_);
        const f32x4* s0 = (const f32x4*)r0;
        const f32x4* s1 = (const f32x4*)(r0 + D_);
        a = s0[0]; bb = s0[1]; c = s1[0]; d = s1[1];
    };
    auto writeV = [&](char* buf, f32x4 a, f32x4 bb, f32x4 c, f32x4 d) {
        #pragma unroll
        for (int j = 0; j < 4; ++j) {
            bf16x2v p0; p0[0] = (__bf16)a[j];  p0[1] = (__bf16)c[j];
            *(bf16x2v*)(buf + swz(dg * 8 + j, kp * 4)) = p0;
            bf16x2v p1; p1[0] = (__bf16)bb[j]; p1[1] = (__bf16)d[j];
            *(bf16x2v*)(buf + swz(dg * 8 + 4 + j, kp * 4)) = p1;
        }
    };
    // coalesced mask load: 4 instrs, each 4 rows x 256B contiguous
    auto loadM = [&](int kc, i32x4& m0, i32x4& m1, i32x4& m2, i32x4& m3) {
        const int* p = mbase + kc * 64;
        m0 = *(const i32x4*)(p);
        m1 = *(const i32x4*)(p + 4 * L_);
        m2 = *(const i32x4*)(p + 8 * L_);
        m3 = *(const i32x4*)(p + 12 * L_);
    };

    float rS = 0.f;
    float inv = 0.f;

    auto compute1 = [&](const char* KB, int kc, i32x4 m0, i32x4 m1, i32x4 m2, i32x4 m3) {
        // redistribute mask bits: producer lane l owns rows (l>>4)+4j, cols (l&15)*4..+3
        auto nib = [](i32x4 m) -> unsigned {
            return (m[0] ? 1u : 0u) | (m[1] ? 2u : 0u) | (m[2] ? 4u : 0u) | (m[3] ? 8u : 0u);
        };
        Mn32[w][l] = nib(m0) | (nib(m1) << 8) | (nib(m2) << 16) | (nib(m3) << 24);
        asm volatile("s_waitcnt lgkmcnt(0)" ::: "memory");  // same-wave xchg
        unsigned mbits = 0;
        const int sh = (lq >> 2) * 8;
        #pragma unroll
        for (int sub = 0; sub < 4; ++sub) {
            unsigned nb = (Mn32[w][(lq & 3) * 16 + sub * 4 + g] >> sh) & 0xFu;
            mbits |= nb << (sub * 4);
        }
        float part = 0.f;
        #pragma unroll
        for (int sub = 0; sub < 4; ++sub) {
            bf16x8v a0 = *(const bf16x8v*)(KB + swz(sub * 16 + lq, g * 16));
            bf16x8v a1 = *(const bf16x8v*)(KB + swz(sub * 16 + lq, 64 + g * 16));
            f32x4 s = {0.f, 0.f, 0.f, 0.f};
            s = __builtin_amdgcn_mfma_f32_16x16x32_bf16(a0, qf0, s, 0, 0, 0);
            s = __builtin_amdgcn_mfma_f32_16x16x32_bf16(a1, qf1, s, 0, 0, 0);
            #pragma unroll
            for (int r = 0; r < 4; ++r) {
                bool mm = (mbits >> (sub * 4 + r)) & 1u;
                float y = mm ? (fminf(fmaxf(s[r], -15.f), 15.f) - 15.f) : -1e30f;
                part += __expf(y);        // exp(-1e30) = 0
            }
        }
        rS += part;
        Ml[kc][t] = (unsigned short)mbits;
    };

    f32x4 acc[4];
    #pragma unroll
    for (int i = 0; i < 4; ++i) acc[i] = (f32x4){0.f, 0.f, 0.f, 0.f};

    auto compute2 = [&](const char* KB, const char* VB, int kc) {
        const unsigned mbits = Ml[kc][t];
        char* PFw = PfB[w];
        #pragma unroll
        for (int sub = 0; sub < 4; ++sub) {
            bf16x8v a0 = *(const bf16x8v*)(KB + swz(sub * 16 + lq, g * 16));
            bf16x8v a1 = *(const bf16x8v*)(KB + swz(sub * 16 + lq, 64 + g * 16));
            f32x4 s = {0.f, 0.f, 0.f, 0.f};
            s = __builtin_amdgcn_mfma_f32_16x16x32_bf16(a0, qf0, s, 0, 0, 0);
            s = __builtin_amdgcn_mfma_f32_16x16x32_bf16(a1, qf1, s, 0, 0, 0);
            f32x4 pv; bf16x4v pb;
            #pragma unroll
            for (int r = 0; r < 4; ++r) {
                bool mm = (mbits >> (sub * 4 + r)) & 1u;
                float y = mm ? (fminf(fmaxf(s[r], -15.f), 15.f) - 15.f) : -1e30f;
                float p = __expf(y) * inv;
                pv[r] = p; pb[r] = (__bf16)p;
            }
            *(f32x4*)(PFw + swzF(lq, (sub * 16 + g * 4) * 4)) = pv;   // f32 stage
            *(bf16x4v*)(PwB[w] + swz(lq, (sub * 16 + g * 4) * 2)) = pb;
        }
        // PV MFMAs (same-wave LDS RAW)
        #pragma unroll
        for (int ks = 0; ks < 2; ++ks) {
            bf16x8v pa = *(const bf16x8v*)(PwB[w] + swz(lq, ks * 64 + g * 16));
            #pragma unroll
            for (int dt = 0; dt < 4; ++dt) {
                bf16x8v vb = *(const bf16x8v*)(VB + swz(dt * 16 + lq, ks * 64 + g * 16));
                acc[dt] = __builtin_amdgcn_mfma_f32_16x16x32_bf16(pa, vb, acc[dt], 0, 0, 0);
            }
        }
        // coalesced attn store: 4 instrs x (4 rows x 256 B contiguous)
        #pragma unroll
        for (int j = 0; j < 4; ++j) {
            const int row = (l >> 4) + 4 * j;
            const int col = (l & 15) * 4;
            f32x4 o = *(const f32x4*)(PFw + swzF(row, col * 4));
            *(f32x4*)(attng + (qwrow + row) * L_ + kc * 64 + col) = o;
        }
    };

    // prefetch register sets (A = even tiles, B = odd tiles)
    f32x4 kA0, kA1, kA2, kA3, kB0, kB1, kB2, kB3;
    f32x4 vA0, vA1, vA2, vA3, vB0, vB1, vB2, vB3;
    i32x4 mA0, mA1, mA2, mA3, mB0, mB1, mB2, mB3;

    // ======================= PASS 1: masked exp-sum =======================
    loadK(0, kA0, kA1, kA2, kA3);
    loadM(0, mA0, mA1, mA2, mA3);
    writeK(KtB[0], kA0, kA1, kA2, kA3);      // one-time stall
    loadK(1, kB0, kB1, kB2, kB3);
    loadM(1, mB0, mB1, mB2, mB3);
    bar();
    #pragma unroll 1
    for (int kc = 0; kc < NKC; kc += 2) {
        { int kn = (kc + 2 < NKC) ? kc + 2 : NKC - 1; loadK(kn, kA0, kA1, kA2, kA3); }
        compute1(KtB[0], kc, mA0, mA1, mA2, mA3);
        { int kn = (kc + 2 < NKC) ? kc + 2 : NKC - 1; loadM(kn, mA0, mA1, mA2, mA3); }
        writeK(KtB[1], kB0, kB1, kB2, kB3);
        bar();
        { int kn = (kc + 3 < NKC) ? kc + 3 : NKC - 1; loadK(kn, kB0, kB1, kB2, kB3); }
        compute1(KtB[1], kc + 1, mB0, mB1, mB2, mB3);
        { int kn = (kc + 3 < NKC) ? kc + 3 : NKC - 1; loadM(kn, mB0, mB1, mB2, mB3); }
        writeK(KtB[0], kA0, kA1, kA2, kA3);
        bar();
    }

    // issue pass-2 first tiles, then reduce (overlap load latency)
    loadK(0, kA0, kA1, kA2, kA3);
    loadV(0, vA0, vA1, vA2, vA3);
    rS += __shfl_xor(rS, 16, 64);
    rS += __shfl_xor(rS, 32, 64);
    inv = 1.f / (rS + 1e-6f);

    // ======================= PASS 2: attn + PV =======================
    writeK(KtB[0], kA0, kA1, kA2, kA3);
    writeV(VtB[0], vA0, vA1, vA2, vA3);
    loadK(1, kB0, kB1, kB2, kB3);
    loadV(1, vB0, vB1, vB2, vB3);
    bar();
    #pragma unroll 1
    for (int kc = 0; kc < NKC; kc += 2) {
        { int kn = (kc + 2 < NKC) ? kc + 2 : NKC - 1;
          loadK(kn, kA0, kA1, kA2, kA3); loadV(kn, vA0, vA1, vA2, vA3); }
        compute2(KtB[0], VtB[0], kc);
        writeK(KtB[1], kB0, kB1, kB2, kB3);
        writeV(VtB[1], vB0, vB1, vB2, vB3);
        bar();
        { int kn = (kc + 3 < NKC) ? kc + 3 : NKC - 1;
          loadK(kn, kB0, kB1, kB2, kB3); loadV(kn, vB0, vB1, vB2, vB3); }
        compute2(KtB[1], VtB[1], kc + 1);
        writeK(KtB[0], kA0, kA1, kA2, kA3);
        writeV(VtB[0], vA0, vA1, vA2, vA3);
        bar();
    }

    // epilogue: acc row = q-local (g*4+r), col = d (dt*16+lq)
    #pragma unroll
    for (int dt = 0; dt < 4; ++dt) {
        #pragma unroll
        for (int r = 0; r < 4; ++r) {
            outg[((size_t)b * L_ + (q0 + w * 16 + g * 4 + r)) * D_ + dt * 16 + lq] = acc[dt][r];
        }
    }
}

extern "C" void kernel_launch(void* const* d_in, const int* in_sizes, int n_in,
                              void* d_out, int out_size, void* d_ws, size_t ws_size,
                              hipStream_t stream) {
    (void)in_sizes; (void)n_in; (void)out_size; (void)d_ws; (void)ws_size;
    const float* q = (const float*)d_in[0];
    const float* k = (const float*)d_in[1];
    const float* v = (const float*)d_in[2];
    const int*   m = (const int*)d_in[3];
    float* out  = (float*)d_out;
    float* attn = out + (size_t)B_ * L_ * D_;
    dim3 grid(B_ * (L_ / 64));   // 512
    dim3 block(256);
    hipLaunchKernelGGL(sdpa_kernel, grid, block, 0, stream, q, k, v, m, out, attn);
}